// Round 1
// 1055.519 us; speedup vs baseline: 1.0880x; 1.0880x over previous
//
#include <hip/hip_runtime.h>
#include <hip/hip_bf16.h>
#include <float.h>
#include <stdint.h>

#define KCONST 750.0f
#define M 256
#define N_TOT 50000
#define NS 50048          // padded score row stride (= 64*782)
#define D 3072
#define BN 64
#define BK 64
#define KIT (D / BK)      // 48 K-iterations
#define ASTRIDE 72        // bf16 elems per A row (pad 8 -> 2-way-free LDS banks)
#define BSTRIDE 72        // bf16 elems per B row
#define TOPK 16
#define NCAND 32

typedef __bf16 bf16_t;
typedef bf16_t bf16x8 __attribute__((ext_vector_type(8)));
typedef float f32x4 __attribute__((ext_vector_type(4)));

// ---- ws layout (bytes) ----
#define OFF_WMAX   0
#define OFF_A      256                                  // bf16[KIT*256*ASTRIDE] = 1,769,472 B
#define OFF_SCORES (OFF_A + KIT * 256 * ASTRIDE * 2)    // f32[256*NS] = 51,249,152 B
#define OFF_CAND   (OFF_SCORES + M * NS * 4)            // int32[256*32]

__device__ __forceinline__ void gl_lds_16(const void* g, void* l) {
    __builtin_amdgcn_global_load_lds((const __attribute__((address_space(1))) void*)g,
                                     (__attribute__((address_space(3))) void*)l, 16, 0, 0);
}

// ---------------- kernel 1: max(w) ----------------
__global__ __launch_bounds__(1024) void k_wmax(const float* __restrict__ w,
                                               float* __restrict__ wmax_out) {
    __shared__ float red[16];
    int t = threadIdx.x;                     // 1024 threads
    float m = -FLT_MAX;
    // vector body: 12 rounds x 4096 floats = 49152
    const f32x4* w4 = (const f32x4*)w;
#pragma unroll 4
    for (int r = 0; r < 12; ++r) {
        f32x4 v = w4[r * 1024 + t];
        m = fmaxf(m, fmaxf(fmaxf(v.x, v.y), fmaxf(v.z, v.w)));
    }
    for (int j = 49152 + t; j < N_TOT; j += 1024) m = fmaxf(m, w[j]);
    for (int o = 32; o > 0; o >>= 1) m = fmaxf(m, __shfl_down(m, o, 64));
    if ((t & 63) == 0) red[t >> 6] = m;
    __syncthreads();
    if (t == 0) {
        float r = red[0];
        for (int i = 1; i < 16; ++i) r = fmaxf(r, red[i]);
        *wmax_out = r;
    }
}

// ---------------- kernel 2: X_tilde f32 -> bf16, K-tiled + padded ----------------
// layout: wsA[kb][m][ASTRIDE], pad cols zeroed (never read by MFMA, but keep clean)
__global__ void k_cvtA(const float* __restrict__ Xt, bf16_t* __restrict__ wsA) {
    int idx = blockIdx.x * 256 + threadIdx.x;
    const int total = KIT * 256 * ASTRIDE;
    if (idx < total) {
        int c = idx % ASTRIDE;
        int m = (idx / ASTRIDE) & 255;
        int kb = idx / (ASTRIDE * 256);
        float v = (c < BK) ? Xt[m * D + kb * BK + c] : 0.0f;
        wsA[idx] = (bf16_t)v;
    }
}

// ---------------- kernel 3: scoring GEMM ----------------
// scores[i][j] = |X_j|^2 + wp_j^2 - 2 * dot(Xt_i, X_j)   (|q_i|^2 dropped: row-constant)
__global__ __launch_bounds__(256) void k_gemm(
        const bf16_t* __restrict__ wsA, const float* __restrict__ X,
        const float* __restrict__ w, const float* __restrict__ wmax_p,
        float* __restrict__ scores) {
    __shared__ __align__(16) bf16_t As[256 * ASTRIDE];   // 36 KB
    __shared__ __align__(16) bf16_t Bs[BN * BSTRIDE];    // 9 KB
    __shared__ float norm4[256];
    __shared__ float nrow[BN];

    const int tid  = threadIdx.x;
    const int wave = tid >> 6;
    const int lane = tid & 63;
    const int q    = lane >> 4;      // quad 0..3
    const int r16  = lane & 15;
    const int j0   = blockIdx.x * BN;

    // B staging mapping: thread -> (row br, 16-col chunk bc); row constant across K
    const int br = tid >> 2;
    const int bc = (tid & 3) * 16;
    const int jrow = min(j0 + br, N_TOT - 1);
    const float* xrow = X + (size_t)jrow * D + bc;

    f32x4 acc[4][4] = {};
    float nacc = 0.f;

    for (int kb = 0; kb < KIT; ++kb) {
        __syncthreads();
        // --- A tile: ws (L2-resident, pre-padded) -> LDS via async DMA, 16B/lane
        {
            const bf16_t* src = wsA + (size_t)kb * (256 * ASTRIDE);
#pragma unroll
            for (int i = 0; i < 9; ++i) {
                int chunk = (wave * 9 + i) * 64;              // 16B chunk id (wave-uniform base)
                gl_lds_16(src + (size_t)(chunk + lane) * 8, As + (size_t)chunk * 8);
            }
        }
        // --- B tile: f32 global -> regs -> bf16 -> LDS, + norm accumulation
        {
            const float* xp = xrow + kb * BK;
            f32x4 v0 = *(const f32x4*)(xp);
            f32x4 v1 = *(const f32x4*)(xp + 4);
            f32x4 v2 = *(const f32x4*)(xp + 8);
            f32x4 v3 = *(const f32x4*)(xp + 12);
            nacc += v0.x*v0.x + v0.y*v0.y + v0.z*v0.z + v0.w*v0.w;
            nacc += v1.x*v1.x + v1.y*v1.y + v1.z*v1.z + v1.w*v1.w;
            nacc += v2.x*v2.x + v2.y*v2.y + v2.z*v2.z + v2.w*v2.w;
            nacc += v3.x*v3.x + v3.y*v3.y + v3.z*v3.z + v3.w*v3.w;
            bf16x8 b0, b1;
            b0[0]=(bf16_t)v0.x; b0[1]=(bf16_t)v0.y; b0[2]=(bf16_t)v0.z; b0[3]=(bf16_t)v0.w;
            b0[4]=(bf16_t)v1.x; b0[5]=(bf16_t)v1.y; b0[6]=(bf16_t)v1.z; b0[7]=(bf16_t)v1.w;
            b1[0]=(bf16_t)v2.x; b1[1]=(bf16_t)v2.y; b1[2]=(bf16_t)v2.z; b1[3]=(bf16_t)v2.w;
            b1[4]=(bf16_t)v3.x; b1[5]=(bf16_t)v3.y; b1[6]=(bf16_t)v3.z; b1[7]=(bf16_t)v3.w;
            *(bf16x8*)&Bs[br * BSTRIDE + bc]     = b0;
            *(bf16x8*)&Bs[br * BSTRIDE + bc + 8] = b1;
        }
        __syncthreads();
        // --- compute: wave owns M rows [wave*64, wave*64+64), all BN cols
#pragma unroll
        for (int ks = 0; ks < 2; ++ks) {
            bf16x8 av[4], bv[4];
#pragma unroll
            for (int mi = 0; mi < 4; ++mi)
                av[mi] = *(const bf16x8*)&As[(wave*64 + mi*16 + r16) * ASTRIDE + ks*32 + q*8];
#pragma unroll
            for (int ni = 0; ni < 4; ++ni)
                bv[ni] = *(const bf16x8*)&Bs[(ni*16 + r16) * BSTRIDE + ks*32 + q*8];
#pragma unroll
            for (int mi = 0; mi < 4; ++mi)
#pragma unroll
                for (int ni = 0; ni < 4; ++ni)
                    acc[mi][ni] = __builtin_amdgcn_mfma_f32_16x16x32_bf16(
                        av[mi], bv[ni], acc[mi][ni], 0, 0, 0);
        }
    }

    // --- per-row norms: reduce 4 partials/row, add wp^2, invalidate tail rows
    norm4[tid] = nacc;
    __syncthreads();
    if (tid < BN) {
        float s = norm4[tid*4] + norm4[tid*4+1] + norm4[tid*4+2] + norm4[tid*4+3];
        int j = j0 + tid;
        if (j < N_TOT) {
            float wp = (*wmax_p - w[j]) * (1.0f / KCONST);
            nrow[tid] = s + wp * wp;
        } else {
            nrow[tid] = FLT_MAX;
        }
    }
    __syncthreads();

    // --- write scores. C/D layout: col = lane&15 (n), row = quad*4+reg (m)
    float nb[4];
#pragma unroll
    for (int ni = 0; ni < 4; ++ni) nb[ni] = nrow[ni*16 + r16];
#pragma unroll
    for (int mi = 0; mi < 4; ++mi) {
        int row = wave*64 + mi*16 + q*4;
#pragma unroll
        for (int ni = 0; ni < 4; ++ni) {
            float* sp = scores + (size_t)row * NS + (j0 + ni*16 + r16);
#pragma unroll
            for (int rg = 0; rg < 4; ++rg)
                sp[(size_t)rg * NS] = nb[ni] - 2.0f * acc[mi][ni][rg];
        }
    }
}

// ---------------- kernel 4: per-query top-32 candidates ----------------
// per-thread sorted top-8 list insert; j visited in increasing order per thread,
// so ties keep the smaller index (matches stable jax top_k)
__device__ __forceinline__ void ins8(float (&bs)[8], int (&bi)[8], float s, int j) {
    if (s < bs[7]) {
        float cs = s; int ci = j;
#pragma unroll
        for (int p = 0; p < 8; ++p) {
            if (cs < bs[p]) {
                float tf = bs[p]; bs[p] = cs; cs = tf;
                int   ti = bi[p]; bi[p] = ci; ci = ti;
            }
        }
    }
}

__global__ __launch_bounds__(256) void k_topk(const float* __restrict__ scores,
                                              int* __restrict__ cand) {
    __shared__ float wv[2][4];
    __shared__ int   wj[2][4];
    const int qrow = blockIdx.x;
    const int tid = threadIdx.x, wave = tid >> 6, lane = tid & 63;
    const float* srow = scores + (size_t)qrow * NS;

    float bs[8]; int bi[8];
#pragma unroll
    for (int p = 0; p < 8; ++p) { bs[p] = FLT_MAX; bi[p] = 0x7fffffff; }

    // --- vectorized streaming: 12 rounds, each thread owns 16 consecutive floats
    // (4x dwordx4 in flight per lane -> BW-bound, not latency-bound)
#pragma unroll 2
    for (int r = 0; r < 12; ++r) {
        const int base = r * 4096 + tid * 16;
        const f32x4 v0 = *(const f32x4*)(srow + base);
        const f32x4 v1 = *(const f32x4*)(srow + base + 4);
        const f32x4 v2 = *(const f32x4*)(srow + base + 8);
        const f32x4 v3 = *(const f32x4*)(srow + base + 12);
        ins8(bs, bi, v0.x, base + 0);  ins8(bs, bi, v0.y, base + 1);
        ins8(bs, bi, v0.z, base + 2);  ins8(bs, bi, v0.w, base + 3);
        ins8(bs, bi, v1.x, base + 4);  ins8(bs, bi, v1.y, base + 5);
        ins8(bs, bi, v1.z, base + 6);  ins8(bs, bi, v1.w, base + 7);
        ins8(bs, bi, v2.x, base + 8);  ins8(bs, bi, v2.y, base + 9);
        ins8(bs, bi, v2.z, base + 10); ins8(bs, bi, v2.w, base + 11);
        ins8(bs, bi, v3.x, base + 12); ins8(bs, bi, v3.y, base + 13);
        ins8(bs, bi, v3.z, base + 14); ins8(bs, bi, v3.w, base + 15);
    }
    // scalar tail: 49152..49999
    for (int j = 49152 + tid; j < N_TOT; j += 256) {
        ins8(bs, bi, srow[j], j);
    }

    // --- extract global 32 smallest; ping-pong LDS -> 1 barrier per iteration
    int cur = 0;
    for (int it = 0; it < NCAND; ++it) {
        float v = bs[0]; int jj = bi[0];
        for (int o = 32; o > 0; o >>= 1) {
            float ov = __shfl_down(v, o, 64);
            int   oj = __shfl_down(jj, o, 64);
            if (ov < v || (ov == v && oj < jj)) { v = ov; jj = oj; }
        }
        if (lane == 0) { wv[cur][wave] = v; wj[cur][wave] = jj; }
        __syncthreads();
        float gv = wv[cur][0]; int gj = wj[cur][0];
#pragma unroll
        for (int k2 = 1; k2 < 4; ++k2) {
            float vv = wv[cur][k2]; int vj = wj[cur][k2];
            if (vv < gv || (vv == gv && vj < gj)) { gv = vv; gj = vj; }
        }
        if (tid == 0) cand[qrow * NCAND + it] = gj;
        if (bi[0] == gj) {   // unique owner pops
#pragma unroll
            for (int p = 0; p < 7; ++p) { bs[p] = bs[p+1]; bi[p] = bi[p+1]; }
            bs[7] = FLT_MAX; bi[7] = 0x7fffffff;
        }
        cur ^= 1;            // next iter writes the other buffer; the barrier above
                             // already separates this iter's reads from that write
    }
}

// ---------------- kernel 5: exact re-rank (f32 L2) + L1 activations + max ----------------
__global__ __launch_bounds__(256) void k_final(
        const float* __restrict__ Xt, const float* __restrict__ X,
        const float* __restrict__ w, const float* __restrict__ wmax_p,
        const int* __restrict__ cand, float* __restrict__ out) {
    __shared__ __align__(16) f32x4 xtl[D / 4];   // 12 KB query row
    __shared__ float d2s[NCAND], acts[NCAND];
    __shared__ int   js[NCAND];
    const int qrow = blockIdx.x;
    const int tid = threadIdx.x, wave = tid >> 6, lane = tid & 63;

    for (int i = tid; i < D / 4; i += 256) xtl[i] = ((const f32x4*)(Xt + (size_t)qrow * D))[i];
    __syncthreads();
    const float wmax = *wmax_p;

    for (int c = wave; c < NCAND; c += 4) {
        int j = cand[qrow * NCAND + c];
        const f32x4* xr = (const f32x4*)(X + (size_t)j * D);
        float l1 = 0.f, l2 = 0.f;
#pragma unroll
        for (int ii = 0; ii < D / 4 / 64; ++ii) {    // 12 iters, compile-time -> batched loads
            int i = lane + ii * 64;
            f32x4 a = xr[i], b = xtl[i];
            float d0 = a.x - b.x, d1 = a.y - b.y, d2_ = a.z - b.z, d3 = a.w - b.w;
            l1 += fabsf(d0) + fabsf(d1) + fabsf(d2_) + fabsf(d3);
            l2 += d0*d0 + d1*d1 + d2_*d2_ + d3*d3;
        }
        for (int o = 32; o > 0; o >>= 1) {
            l1 += __shfl_down(l1, o, 64);
            l2 += __shfl_down(l2, o, 64);
        }
        if (lane == 0) {
            float wj = w[j];
            float wp = (wmax - wj) * (1.0f / KCONST);
            d2s[c]  = l2 + wp * wp;     // exact augmented squared L2
            acts[c] = wj - KCONST * l1;
            js[c]   = j;
        }
    }
    __syncthreads();
    // wave-parallel rank: lane c computes how many candidates beat candidate c
    // (stable tie-break by index); keep acts of rank < TOPK, shuffle-max
    if (wave == 0) {
        float act = -FLT_MAX;
        if (lane < NCAND) {
            float dc = d2s[lane]; int jc = js[lane];
            int rank = 0;
#pragma unroll
            for (int c2 = 0; c2 < NCAND; ++c2)
                if (d2s[c2] < dc || (d2s[c2] == dc && js[c2] < jc)) ++rank;
            if (rank < TOPK) act = acts[lane];
        }
        for (int o = 32; o > 0; o >>= 1) act = fmaxf(act, __shfl_down(act, o, 64));
        if (lane == 0) out[qrow] = act;
    }
}

extern "C" void kernel_launch(void* const* d_in, const int* in_sizes, int n_in,
                              void* d_out, int out_size, void* d_ws, size_t ws_size,
                              hipStream_t stream) {
    const float* Xt = (const float*)d_in[0];   // [256, 3072]
    const float* X  = (const float*)d_in[1];   // [50000, 3072]
    const float* w  = (const float*)d_in[2];   // [50000, 1]
    float* out = (float*)d_out;                // [256]

    char* ws = (char*)d_ws;
    float*  wmaxp  = (float*)(ws + OFF_WMAX);
    bf16_t* wsA    = (bf16_t*)(ws + OFF_A);
    float*  scores = (float*)(ws + OFF_SCORES);
    int*    cand   = (int*)(ws + OFF_CAND);

    k_wmax<<<1, 1024, 0, stream>>>(w, wmaxp);
    {
        int total = KIT * 256 * ASTRIDE;
        k_cvtA<<<(total + 255) / 256, 256, 0, stream>>>(Xt, wsA);
    }
    k_gemm<<<(N_TOT + BN - 1) / BN, 256, 0, stream>>>(wsA, X, w, wmaxp, scores);
    k_topk<<<M, 256, 0, stream>>>(scores, cand);
    k_final<<<M, 256, 0, stream>>>(Xt, X, w, wmaxp, cand, out);
}